// Round 1
// baseline (973.459 us; speedup 1.0000x reference)
//
#include <hip/hip_runtime.h>
#include <hip/hip_bf16.h>

#define LN_EPS 1e-6f

typedef __attribute__((ext_vector_type(8))) short bf16x8;
typedef __attribute__((ext_vector_type(4))) float fx4;

__device__ __forceinline__ unsigned short f2bf(float f) {
    union { __hip_bfloat16 b; unsigned short u; } cv;
    cv.b = __float2bfloat16(f);
    return cv.u;
}

// block-wide sum of (a, b) across blockDim.x (multiple of 64) threads; result broadcast
__device__ __forceinline__ float2 block_sum2(float a, float b) {
    __shared__ float sa[8], sb[8];
    #pragma unroll
    for (int off = 1; off < 64; off <<= 1) {
        a += __shfl_xor(a, off);
        b += __shfl_xor(b, off);
    }
    int w = threadIdx.x >> 6;
    if ((threadIdx.x & 63) == 0) { sa[w] = a; sb[w] = b; }
    __syncthreads();
    int nw = blockDim.x >> 6;
    float ra = 0.f, rb = 0.f;
    for (int i = 0; i < nw; ++i) { ra += sa[i]; rb += sb[i]; }
    __syncthreads();
    return make_float2(ra, rb);
}

// ---------- pad dtype detector: u8 bool vs int32 ----------
__global__ void k_pad(const unsigned char* __restrict__ p, float* __restrict__ padf) {
    __shared__ int cnt;
    int t = threadIdx.x;                  // 512 threads
    if (t == 0) cnt = 0;
    __syncthreads();
    if (p[t]) atomicAdd(&cnt, 1);
    __syncthreads();
    float v;
    if (cnt > 256) v = p[t] ? 1.f : 0.f;                       // u8 bools
    else           v = ((const int*)p)[t] ? 1.f : 0.f;          // int32 (or f32 bits) per elem
    padf[t] = v;
}

// ---------- conv0 (3x3, 4->32) + bias + LN(32) + ReLU -> bf16 ----------
__global__ __launch_bounds__(256) void k_conv0(
    const float* __restrict__ x, const float* __restrict__ w,
    const float* __restrict__ bias, const float* __restrict__ lns, const float* __restrict__ lnb,
    unsigned short* __restrict__ a0)
{
    int pid = blockIdx.x * 256 + threadIdx.x;   // 512*7056 exactly
    int img = pid / 7056;
    int p = pid - img * 7056;
    int py = p / 84;
    int px = p - py * 84;

    float acc[32];
    #pragma unroll
    for (int c = 0; c < 32; ++c) acc[c] = bias[c];

    #pragma unroll
    for (int dy = 0; dy < 3; ++dy) {
        int yy = py + dy - 1;
        if (yy < 0 || yy >= 84) continue;
        #pragma unroll
        for (int dx = 0; dx < 3; ++dx) {
            int xx = px + dx - 1;
            if (xx < 0 || xx >= 84) continue;
            float4 v = *reinterpret_cast<const float4*>(x + ((size_t)img * 7056 + yy * 84 + xx) * 4);
            const float* wt = w + (dy * 3 + dx) * 128;   // (3,3,4,32)
            #pragma unroll
            for (int ci = 0; ci < 4; ++ci) {
                float xv = (&v.x)[ci];
                #pragma unroll
                for (int c = 0; c < 32; ++c)
                    acc[c] = fmaf(xv, wt[ci * 32 + c], acc[c]);
            }
        }
    }
    float m = 0.f;
    #pragma unroll
    for (int c = 0; c < 32; ++c) m += acc[c];
    m *= (1.f / 32.f);
    float var = 0.f;
    #pragma unroll
    for (int c = 0; c < 32; ++c) { float d = acc[c] - m; var = fmaf(d, d, var); }
    var *= (1.f / 32.f);
    float inv = rsqrtf(var + LN_EPS);
    unsigned short ob[32];
    #pragma unroll
    for (int c = 0; c < 32; ++c) {
        float o = (acc[c] - m) * inv * lns[c] + lnb[c];
        ob[c] = f2bf(fmaxf(o, 0.f));
    }
    uint4* dst = reinterpret_cast<uint4*>(a0 + (size_t)pid * 32);
    #pragma unroll
    for (int g = 0; g < 4; ++g) {
        uint4 pk;
        pk.x = (unsigned)ob[g * 8 + 0] | ((unsigned)ob[g * 8 + 1] << 16);
        pk.y = (unsigned)ob[g * 8 + 2] | ((unsigned)ob[g * 8 + 3] << 16);
        pk.z = (unsigned)ob[g * 8 + 4] | ((unsigned)ob[g * 8 + 5] << 16);
        pk.w = (unsigned)ob[g * 8 + 6] | ((unsigned)ob[g * 8 + 7] << 16);
        dst[g] = pk;
    }
}

// ---------- conv1 weight repack: (3,3,32,64) f32 -> wtb[tap][co][kg][j] bf16 ----------
__global__ void k_wprep(const float* __restrict__ w, unsigned short* __restrict__ wtb) {
    int idx = blockIdx.x * 256 + threadIdx.x;   // 18432 exactly
    int j  = idx & 7;
    int kg = (idx >> 3) & 3;
    int co = (idx >> 5) & 63;
    int tp = idx >> 11;
    float v = w[((size_t)tp * 32 + kg * 8 + j) * 64 + co];
    wtb[idx] = f2bf(v);
}

// ---------- conv1 (3x3, 32->64) bf16 MFMA + bias + LN(64) + ReLU + mean-pool ----------
__global__ __launch_bounds__(256) void k_conv1(
    const unsigned short* __restrict__ a0, const unsigned short* __restrict__ wtb,
    const float* __restrict__ bias, const float* __restrict__ lns, const float* __restrict__ lnb,
    float* __restrict__ pooled)
{
    __shared__ float pool_s[64];
    if (threadIdx.x < 64) pool_s[threadIdx.x] = 0.f;
    __syncthreads();

    const int lane = threadIdx.x & 63;
    const int wave = threadIdx.x >> 6;
    const int lo = lane & 15;     // A-row (pixel) for loads; also co offset for D
    const int kg = lane >> 4;     // k-group
    const int img  = blockIdx.x / 111;
    const int tile = blockIdx.x - img * 111;
    const int pbase = tile * 64 + wave * 16;
    const int p = pbase + lo;
    const int py = p / 84, px = p - py * 84;
    const bool pvld = p < 7056;

    fx4 acc[4];
    #pragma unroll
    for (int n = 0; n < 4; ++n) acc[n] = (fx4){0.f, 0.f, 0.f, 0.f};

    const size_t ibase = (size_t)img * 7056;
    #pragma unroll
    for (int t = 0; t < 9; ++t) {
        const int dy = t / 3 - 1, dx = t % 3 - 1;
        int yy = py + dy, xx = px + dx;
        bf16x8 af = (bf16x8){0, 0, 0, 0, 0, 0, 0, 0};
        if (pvld && yy >= 0 && yy < 84 && xx >= 0 && xx < 84) {
            af = *reinterpret_cast<const bf16x8*>(
                reinterpret_cast<const short*>(a0) + (ibase + yy * 84 + xx) * 32 + kg * 8);
        }
        #pragma unroll
        for (int n = 0; n < 4; ++n) {
            bf16x8 bfr = *reinterpret_cast<const bf16x8*>(
                reinterpret_cast<const short*>(wtb) + ((t * 64 + n * 16 + lo) * 4 + kg) * 8);
            acc[n] = __builtin_amdgcn_mfma_f32_16x16x32_bf16(af, bfr, acc[n], 0, 0, 0);
        }
    }

    // D: lane holds pixel (pbase + kg*4 + r), channel (n*16 + lo) in acc[n][r]
    float bs[4], ss[4], bb[4];
    #pragma unroll
    for (int n = 0; n < 4; ++n) {
        int c = n * 16 + lo;
        bs[n] = bias[c]; ss[n] = lns[c]; bb[n] = lnb[c];
    }
    float pv4[4] = {0.f, 0.f, 0.f, 0.f};
    #pragma unroll
    for (int r = 0; r < 4; ++r) {
        float v0 = acc[0][r] + bs[0], v1 = acc[1][r] + bs[1];
        float v2 = acc[2][r] + bs[2], v3 = acc[3][r] + bs[3];
        float s = v0 + v1 + v2 + v3;
        float q = v0 * v0 + v1 * v1 + v2 * v2 + v3 * v3;
        #pragma unroll
        for (int off = 1; off < 16; off <<= 1) {
            s += __shfl_xor(s, off);
            q += __shfl_xor(q, off);
        }
        float m = s * (1.f / 64.f);
        float var = q * (1.f / 64.f) - m * m;
        float inv = rsqrtf(var + LN_EPS);
        int pix = pbase + kg * 4 + r;
        float valid = (pix < 7056) ? 1.f : 0.f;
        pv4[0] += fmaxf((v0 - m) * inv * ss[0] + bb[0], 0.f) * valid;
        pv4[1] += fmaxf((v1 - m) * inv * ss[1] + bb[1], 0.f) * valid;
        pv4[2] += fmaxf((v2 - m) * inv * ss[2] + bb[2], 0.f) * valid;
        pv4[3] += fmaxf((v3 - m) * inv * ss[3] + bb[3], 0.f) * valid;
    }
    #pragma unroll
    for (int n = 0; n < 4; ++n) {
        float v = pv4[n];
        v += __shfl_xor(v, 16);
        v += __shfl_xor(v, 32);
        if (lane < 16) atomicAdd(&pool_s[n * 16 + lane], v);
    }
    __syncthreads();
    if (threadIdx.x < 64) atomicAdd(&pooled[img * 64 + threadIdx.x], pool_s[threadIdx.x]);
}

// ---------- pooled mean -> proj(64->256) + bias + LN ----------
__global__ __launch_bounds__(256) void k_pool_proj(
    const float* __restrict__ pooled, const float* __restrict__ W,
    const float* __restrict__ pb, const float* __restrict__ lns, const float* __restrict__ lnb,
    float* __restrict__ h)
{
    __shared__ float sm[64];
    int row = blockIdx.x, t = threadIdx.x;
    if (t < 64) sm[t] = pooled[row * 64 + t] * (1.f / 7056.f);
    __syncthreads();
    float acc = pb[t];
    #pragma unroll 8
    for (int k = 0; k < 64; ++k) acc = fmaf(sm[k], W[k * 256 + t], acc);
    float2 sq = block_sum2(acc, acc * acc);
    float m = sq.x * (1.f / 256.f);
    float var = sq.y * (1.f / 256.f) - m * m;
    h[row * 256 + t] = (acc - m) * rsqrtf(var + LN_EPS) * lns[t] + lnb[t];
}

// ---------- qkv projection + RoPE -> q,k,v in (b, nh, s, hd) ----------
__global__ __launch_bounds__(256) void k_qkv_rope(
    const float* __restrict__ h, const float* __restrict__ W, const float* __restrict__ bvec,
    float* __restrict__ qb, float* __restrict__ kb, float* __restrict__ vb)
{
    __shared__ float hr[256];
    __shared__ float qkv[768];
    int row = blockIdx.x, t = threadIdx.x;
    hr[t] = h[row * 256 + t];
    __syncthreads();
    #pragma unroll
    for (int m = 0; m < 3; ++m) {
        int col = m * 256 + t;
        float acc = bvec[col];
        #pragma unroll 8
        for (int k = 0; k < 256; ++k) acc = fmaf(hr[k], W[k * 768 + col], acc);
        qkv[col] = acc;
    }
    __syncthreads();
    int b = row >> 5, s = row & 31;
    int hd_i = t >> 6, d = t & 63;
    size_t dst = ((size_t)(b * 4 + hd_i) * 32 + s) * 64 + d;
    int j = d >> 1;
    // inv_freq = 10000^(-2j/64) = 2^(-j * (2/64) * log2(10000))
    float freq = exp2f(-(float)j * 0.41524101186f);
    float ang = (float)s * freq;
    float sn, cs;
    sincosf(ang, &sn, &cs);
    {
        float xe = qkv[t & ~1], xo = qkv[t | 1];
        qb[dst] = (d & 1) ? (xo * cs + xe * sn) : (xe * cs - xo * sn);
    }
    {
        float xe = qkv[256 + (t & ~1)], xo = qkv[256 + (t | 1)];
        kb[dst] = (d & 1) ? (xo * cs + xe * sn) : (xe * cs - xo * sn);
    }
    vb[dst] = qkv[512 + t];
}

// ---------- attention per (b, head): softmax(mask(QK^T*scale)) @ V ----------
__global__ __launch_bounds__(256) void k_attn(
    const float* __restrict__ qb, const float* __restrict__ kb, const float* __restrict__ vb,
    const float* __restrict__ padf, float* __restrict__ y)
{
    __shared__ float Q[32][65], K[32][65], V[32][65], P[32][33];
    int bh = blockIdx.x;              // b*4 + h
    int b = bh >> 2, hh = bh & 3;
    int t = threadIdx.x;
    #pragma unroll
    for (int i = 0; i < 8; ++i) {
        int idx = t + i * 256;        // 0..2047
        int r = idx >> 6, d = idx & 63;
        Q[r][d] = qb[(size_t)bh * 2048 + idx];
        K[r][d] = kb[(size_t)bh * 2048 + idx];
        V[r][d] = vb[(size_t)bh * 2048 + idx];
    }
    __syncthreads();
    int r = t >> 3, k8 = t & 7;
    #pragma unroll
    for (int i = 0; i < 4; ++i) {
        int kk = k8 + i * 8;
        float acc = 0.f;
        #pragma unroll
        for (int d = 0; d < 64; ++d) acc = fmaf(Q[r][d], K[kk][d], acc);
        acc *= 0.125f;
        bool ok = (kk <= r) && (padf[b * 32 + kk] != 0.f);
        P[r][kk] = ok ? acc : -1e9f;
    }
    __syncthreads();
    if (t < 32) {
        float mx = -1e30f;
        #pragma unroll
        for (int kk = 0; kk < 32; ++kk) mx = fmaxf(mx, P[t][kk]);
        float sum = 0.f, e[32];
        #pragma unroll
        for (int kk = 0; kk < 32; ++kk) { e[kk] = __expf(P[t][kk] - mx); sum += e[kk]; }
        float inv = 1.f / sum;
        #pragma unroll
        for (int kk = 0; kk < 32; ++kk) P[t][kk] = e[kk] * inv;
    }
    __syncthreads();
    int d0 = (t & 7) * 8;
    float o[8] = {0.f, 0.f, 0.f, 0.f, 0.f, 0.f, 0.f, 0.f};
    for (int kk = 0; kk < 32; ++kk) {
        float a = P[r][kk];
        #pragma unroll
        for (int jj = 0; jj < 8; ++jj) o[jj] = fmaf(a, V[kk][d0 + jj], o[jj]);
    }
    float* dst = y + ((size_t)(b * 32 + r) * 256 + hh * 64 + d0);
    #pragma unroll
    for (int jj = 0; jj < 8; ++jj) dst[jj] = o[jj];
}

// ---------- attn out-proj + pad mask + LN + residual (in-place h) ----------
__global__ __launch_bounds__(256) void k_attn_out(
    const float* __restrict__ y, const float* __restrict__ W, const float* __restrict__ bvec,
    const float* __restrict__ padf, const float* __restrict__ lns, const float* __restrict__ lnb,
    float* __restrict__ h)
{
    __shared__ float yr[256];
    int row = blockIdx.x, t = threadIdx.x;
    yr[t] = y[row * 256 + t];
    __syncthreads();
    float acc = bvec[t];
    #pragma unroll 8
    for (int k = 0; k < 256; ++k) acc = fmaf(yr[k], W[k * 256 + t], acc);
    acc *= padf[row];
    float2 sq = block_sum2(acc, acc * acc);
    float m = sq.x * (1.f / 256.f);
    float var = sq.y * (1.f / 256.f) - m * m;
    float res = h[row * 256 + t];
    h[row * 256 + t] = (acc - m) * rsqrtf(var + LN_EPS) * lns[t] + lnb[t] + res;
}

// ---------- MLP up (256->512) + ReLU ----------
__global__ __launch_bounds__(256) void k_mlp_up(
    const float* __restrict__ h, const float* __restrict__ W, float* __restrict__ u)
{
    __shared__ float hr[256];
    int row = blockIdx.x, t = threadIdx.x;
    hr[t] = h[row * 256 + t];
    __syncthreads();
    float a0 = 0.f, a1 = 0.f;
    #pragma unroll 8
    for (int k = 0; k < 256; ++k) {
        float hk = hr[k];
        a0 = fmaf(hk, W[k * 512 + t], a0);
        a1 = fmaf(hk, W[k * 512 + 256 + t], a1);
    }
    u[row * 512 + t] = fmaxf(a0, 0.f);
    u[row * 512 + 256 + t] = fmaxf(a1, 0.f);
}

// ---------- MLP down (512->256) + LN + residual (in-place h) ----------
__global__ __launch_bounds__(256) void k_mlp_down(
    const float* __restrict__ u, const float* __restrict__ W,
    const float* __restrict__ lns, const float* __restrict__ lnb, float* __restrict__ h)
{
    __shared__ float ur[512];
    int row = blockIdx.x, t = threadIdx.x;
    ur[t] = u[row * 512 + t];
    ur[t + 256] = u[row * 512 + 256 + t];
    __syncthreads();
    float acc = 0.f;
    #pragma unroll 8
    for (int k = 0; k < 512; ++k) acc = fmaf(ur[k], W[k * 256 + t], acc);
    float2 sq = block_sum2(acc, acc * acc);
    float m = sq.x * (1.f / 256.f);
    float var = sq.y * (1.f / 256.f) - m * m;
    float res = h[row * 256 + t];
    h[row * 256 + t] = (acc - m) * rsqrtf(var + LN_EPS) * lns[t] + lnb[t] + res;
}

// ---------- head (256->18) ----------
__global__ __launch_bounds__(256) void k_head(
    const float* __restrict__ h, const float* __restrict__ W, const float* __restrict__ b,
    float* __restrict__ out)
{
    __shared__ float hr[256];
    int row = blockIdx.x, t = threadIdx.x;
    hr[t] = h[row * 256 + t];
    __syncthreads();
    if (t < 18) {
        float acc = b[t];
        #pragma unroll 8
        for (int k = 0; k < 256; ++k) acc = fmaf(hr[k], W[k * 18 + t], acc);
        out[row * 18 + t] = acc;
    }
}

extern "C" void kernel_launch(void* const* d_in, const int* in_sizes, int n_in,
                              void* d_out, int out_size, void* d_ws, size_t ws_size,
                              hipStream_t stream)
{
    (void)in_sizes; (void)n_in; (void)out_size; (void)ws_size;
    const float* x   = (const float*)d_in[0];
    const unsigned char* pad = (const unsigned char*)d_in[1];
    const float* c0w = (const float*)d_in[2];
    const float* c0b = (const float*)d_in[3];
    const float* l0s = (const float*)d_in[4];
    const float* l0b = (const float*)d_in[5];
    const float* c1w = (const float*)d_in[6];
    const float* c1b = (const float*)d_in[7];
    const float* l1s = (const float*)d_in[8];
    const float* l1b = (const float*)d_in[9];
    const float* pw  = (const float*)d_in[10];
    const float* pb  = (const float*)d_in[11];
    const float* lps = (const float*)d_in[12];
    const float* lpb = (const float*)d_in[13];
    const float* qkvw = (const float*)d_in[14];
    const float* qkvb = (const float*)d_in[15];
    const float* ow  = (const float*)d_in[16];
    const float* obv = (const float*)d_in[17];
    const float* las = (const float*)d_in[18];
    const float* lab = (const float*)d_in[19];
    const float* upw = (const float*)d_in[20];
    const float* dww = (const float*)d_in[21];
    const float* lms = (const float*)d_in[22];
    const float* lmb = (const float*)d_in[23];
    const float* hw  = (const float*)d_in[24];
    const float* hb  = (const float*)d_in[25];
    float* out = (float*)d_out;

    char* ws = (char*)d_ws;
    size_t off = 0;
    auto alloc = [&](size_t bytes) -> void* {
        void* p = ws + off;
        off = (off + bytes + 255) & ~(size_t)255;
        return p;
    };
    unsigned short* a0  = (unsigned short*)alloc((size_t)512 * 7056 * 32 * 2);
    unsigned short* wtb = (unsigned short*)alloc(18432 * 2);
    float* pooled = (float*)alloc(512 * 64 * 4);
    float* padf   = (float*)alloc(512 * 4);
    float* h      = (float*)alloc(512 * 256 * 4);
    float* qb     = (float*)alloc(512 * 256 * 4);
    float* kb     = (float*)alloc(512 * 256 * 4);
    float* vb     = (float*)alloc(512 * 256 * 4);
    float* yb     = (float*)alloc(512 * 256 * 4);
    float* ub     = (float*)alloc(512 * 512 * 4);

    hipMemsetAsync(pooled, 0, 512 * 64 * 4, stream);
    k_pad<<<1, 512, 0, stream>>>(pad, padf);
    k_conv0<<<14112, 256, 0, stream>>>(x, c0w, c0b, l0s, l0b, a0);
    k_wprep<<<72, 256, 0, stream>>>(c1w, wtb);
    k_conv1<<<56832, 256, 0, stream>>>(a0, wtb, c1b, l1s, l1b, pooled);
    k_pool_proj<<<512, 256, 0, stream>>>(pooled, pw, pb, lps, lpb, h);
    for (int i = 0; i < 2; ++i) {
        k_qkv_rope<<<512, 256, 0, stream>>>(h, qkvw + (size_t)i * 256 * 768, qkvb + i * 768, qb, kb, vb);
        k_attn<<<64, 256, 0, stream>>>(qb, kb, vb, padf, yb);
        k_attn_out<<<512, 256, 0, stream>>>(yb, ow + (size_t)i * 256 * 256, obv + i * 256,
                                            padf, las + i * 256, lab + i * 256, h);
        k_mlp_up<<<512, 256, 0, stream>>>(h, upw + (size_t)i * 256 * 512, ub);
        k_mlp_down<<<512, 256, 0, stream>>>(ub, dww + (size_t)i * 512 * 256,
                                            lms + i * 256, lmb + i * 256, h);
    }
    k_head<<<512, 256, 0, stream>>>(h, hw, hb, out);
}